// Round 9
// baseline (228.617 us; speedup 1.0000x reference)
//
#include <hip/hip_runtime.h>
#include <math.h>

#define B_ 2048
#define N_ 256
#define R_ (B_*N_)
#define MU_ 0.1f
#define SIGMA_ 0.2f
#define TILE_M 32
#define GRID_MLP 512
#define ITERS (R_ / TILE_M / GRID_MLP)   // 32

typedef __attribute__((ext_vector_type(8))) short bf16x8;
typedef __attribute__((ext_vector_type(4))) float f32x4;

__device__ __forceinline__ unsigned short f2bf(float x) {  // RNE (weights only)
    union { float f; unsigned u; } v; v.f = x;
    unsigned r = v.u + 0x7fffu + ((v.u >> 16) & 1u);
    return (unsigned short)(r >> 16);
}

// ---- convert fW1/gW1 (256x256 f32, k-major) to bf16 MFMA fragments ----
// short idx = ((kk*16 + ct)*64 + lane)*8 + j ; holds W1[k = kk*32+(lane>>4)*8+j][c = ct*16+(lane&15)]
__global__ void prep_weights(const float* __restrict__ fW1, const float* __restrict__ gW1,
                             unsigned short* __restrict__ wswz) {
    int idx = blockIdx.x * 256 + threadIdx.x;
    if (idx >= 2 * 65536) return;
    int m = idx >> 16, r = idx & 65535;
    int j = r & 7, lane = (r >> 3) & 63, frag = r >> 9;
    int kk = frag >> 4, ct = frag & 15;
    int k = kk * 32 + (lane >> 4) * 8 + j;
    int c = ct * 16 + (lane & 15);
    const float* W = m ? gW1 : fW1;
    wswz[idx] = f2bf(W[k * 256 + c]);
}

// ---- trajectory via wave-parallel prefix-product scan: one wave per batch row ----
__global__ void traj_kernel(const float* __restrict__ ts, const float* __restrict__ x0,
                            const float* __restrict__ eps, float* __restrict__ xs,
                            float* __restrict__ fv) {
    int gid = blockIdx.x * 256 + threadIdx.x;
    int b = gid >> 6, lane = gid & 63;
    int n0 = lane * 4;

    float t0 = ts[n0], t1 = ts[n0 + 1], t2 = ts[n0 + 2], t3 = ts[n0 + 3];
    float t4 = (n0 + 4 < N_) ? ts[n0 + 4] : t3;          // lane 63: h3 = 0
    float h0 = t1 - t0, h1 = t2 - t1, h2 = t3 - t2, h3 = t4 - t3;
    float s0 = sqrtf(h0), s1 = sqrtf(h1), s2 = sqrtf(h2), s3 = sqrtf(h3);

    const float4* e4 = (const float4*)(eps + (size_t)(b * N_ + n0) * 2);
    float4 ea = e4[0], eb = e4[1];
    float f0a = 1.f + MU_ * h0 + SIGMA_ * (ea.x * s0);
    float f0b = 1.f + MU_ * h0 + SIGMA_ * (ea.y * s0);
    float f1a = 1.f + MU_ * h1 + SIGMA_ * (ea.z * s1);
    float f1b = 1.f + MU_ * h1 + SIGMA_ * (ea.w * s1);
    float f2a = 1.f + MU_ * h2 + SIGMA_ * (eb.x * s2);
    float f2b = 1.f + MU_ * h2 + SIGMA_ * (eb.y * s2);
    float f3a = 1.f + MU_ * h3 + SIGMA_ * (eb.z * s3);
    float f3b = 1.f + MU_ * h3 + SIGMA_ * (eb.w * s3);

    float Pa = f0a * f1a * f2a * f3a;
    float Pb = f0b * f1b * f2b * f3b;
    float Sa = Pa, Sb = Pb;
#pragma unroll
    for (int d = 1; d < 64; d <<= 1) {
        float va = __shfl_up(Sa, d);
        float vb = __shfl_up(Sb, d);
        if (lane >= d) { Sa *= va; Sb *= vb; }
    }
    float Ea = __shfl_up(Sa, 1);
    float Eb = __shfl_up(Sb, 1);
    if (lane == 0) { Ea = 1.f; Eb = 1.f; }

    float x0a = x0[2 * b], x0b = x0[2 * b + 1];
    float xa0 = x0a * Ea, xb0 = x0b * Eb;
    float xa1 = xa0 * f0a, xb1 = xb0 * f0b;
    float xa2 = xa1 * f1a, xb2 = xb1 * f1b;
    float xa3 = xa2 * f2a, xb3 = xb2 * f2b;

    float4* xsv = (float4*)(xs + (size_t)(b * N_ + n0) * 2);
    xsv[0] = make_float4(xa0, xb0, xa1, xb1);
    xsv[1] = make_float4(xa2, xb2, xa3, xb3);
    if (lane == 63) fv[b] = xa3 * xa3 + xb3 * xb3;
}

// ---- fused MLP, transposed GEMM: D = W1^T(A, resident regs) @ h0^T(B, LDS) ----
// MERGED f+g kernel: grid 1024, variant MLP = blockIdx&1 (block-uniform), bid = blockIdx>>1.
// Interleaving the two independent MLPs doubles co-residable blocks -> 3 blocks/CU
// (VGPR 84 = 6 waves/SIMD; LDS 4x40448 <= 163840) so VALU/LDS/MFMA phases of different
// blocks overlap (m114 mechanism) instead of convoying at 1 block/CU.
// 512 threads / 8 waves; wave w owns cols [32w, 32w+32); afrag 64 VGPRs.
// SINGLE barrier per tile (round-8 schedule, unchanged).
__global__ __launch_bounds__(512) void mlp_kernel(
        const float* __restrict__ ts, const float* __restrict__ eps, const float* __restrict__ xs,
        const unsigned short* __restrict__ wswz,
        const float* __restrict__ fW0, const float* __restrict__ fb0,
        const float* __restrict__ fb1, const float* __restrict__ fW2, const float* __restrict__ fb2,
        const float* __restrict__ gW0, const float* __restrict__ gb0,
        const float* __restrict__ gb1, const float* __restrict__ gW2, const float* __restrict__ gb2,
        float* __restrict__ Yout, float* __restrict__ zdot) {

    __shared__ __align__(16) unsigned short h0s[2][TILE_M * 256];   // 2 x 16KB, XOR-swizzled rows
    __shared__ float tss[4][TILE_M], txs1[4][TILE_M], txs2[4][TILE_M];
    __shared__ float dws0[4][TILE_M], dws1[4][TILE_M];
    __shared__ float red[2][8][TILE_M];
    __shared__ __align__(16) float sh_b1[256], sh_w20[256], sh_w21[256];

    const int MLP = blockIdx.x & 1;
    const int bid = blockIdx.x >> 1;

    const float* W0 = MLP ? gW0 : fW0;
    const float* b0 = MLP ? gb0 : fb0;
    const float* b1 = MLP ? gb1 : fb1;
    const float* W2 = MLP ? gW2 : fW2;
    const float* b2 = MLP ? gb2 : fb2;
    float* outp     = MLP ? zdot : Yout;

    const int tid  = threadIdx.x;
    const int lane = tid & 63;
    const int w    = tid >> 6;       // wave 0..7: cols [32w, 32w+32)
    const int arow = lane & 15;      // sample index within 16-tile
    const int rg   = lane >> 4;      // k-group / c-subgroup

    const int c0 = (tid & 63) * 4;   // layer0 col base
    const int row0 = (tid >> 6) * 4; // layer0 row base
    f32x4 w0t = *(const f32x4*)(W0 + c0);
    f32x4 w0x = *(const f32x4*)(W0 + 256 + c0);
    f32x4 w0y = *(const f32x4*)(W0 + 512 + c0);
    f32x4 w0bv = *(const f32x4*)(b0 + c0);

    if (tid < 256) {
        sh_b1[tid] = b1[tid];
        if (MLP) { sh_w20[tid] = W2[2 * tid]; sh_w21[tid] = W2[2 * tid + 1]; }
        else     { sh_w20[tid] = W2[tid];     sh_w21[tid] = 0.f; }
    }
    const float b20 = b2[0];
    const float b21 = MLP ? b2[1] : 0.f;

    // resident A-fragments of W1^T: 8 kk x 2 ct x 4 VGPR = 64 VGPRs
    bf16x8 afrag[8][2];
    const bf16x8* wsw8 = (const bf16x8*)(wswz + MLP * 65536);
#pragma unroll
    for (int kk = 0; kk < 8; ++kk)
#pragma unroll
        for (int p = 0; p < 2; ++p)
            afrag[kk][p] = wsw8[(kk * 16 + (w * 2 + p)) * 64 + lane];

    // prologue: stage tiles 0,1 -> scal[0],scal[1]; prefetch tile 2 -> regs
    float p_x1 = 0.f, p_x2 = 0.f, p_t = 0.f, p_tn = 0.f, p_e0 = 0.f, p_e1 = 0.f;
    if (tid < TILE_M) {
#pragma unroll
        for (int tt = 0; tt < 2; ++tt) {
            int r = (bid + tt * GRID_MLP) * TILE_M + tid, n = r & (N_ - 1);
            float2 xv = ((const float2*)xs)[r];
            float tv = ts[n];
            tss[tt][tid] = tv; txs1[tt][tid] = xv.x; txs2[tt][tid] = xv.y;
            if (MLP) {
                float tn = (n < N_ - 1) ? ts[n + 1] : tv;
                float sdt = sqrtf(tn - tv);
                float2 ev = ((const float2*)eps)[r];
                dws0[tt][tid] = ev.x * sdt; dws1[tt][tid] = ev.y * sdt;
            }
        }
        int r = (bid + 2 * GRID_MLP) * TILE_M + tid, n = r & (N_ - 1);
        float2 xv = ((const float2*)xs)[r];
        p_x1 = xv.x; p_x2 = xv.y;
        p_t = ts[n]; p_tn = (n < N_ - 1) ? ts[n + 1] : ts[n];
        if (MLP) { float2 ev = ((const float2*)eps)[r]; p_e0 = ev.x; p_e1 = ev.y; }
    }
    __syncthreads();
    // layer0 tile 0 -> h0s[0]
#pragma unroll
    for (int ii = 0; ii < 4; ++ii) {
        int r = row0 + ii;
        float t = tss[0][r], x1 = txs1[0][r], x2 = txs2[0][r];
        f32x4 h;
#pragma unroll
        for (int j = 0; j < 4; ++j)
            h[j] = fmaf(t, w0t[j], fmaf(x1, w0x[j], fmaf(x2, w0y[j], w0bv[j])));
        unsigned qlo = __builtin_amdgcn_perm(__float_as_uint(fmaxf(h[1], 0.f)),
                                             __float_as_uint(fmaxf(h[0], 0.f)), 0x07060302u);
        unsigned qhi = __builtin_amdgcn_perm(__float_as_uint(fmaxf(h[3], 0.f)),
                                             __float_as_uint(fmaxf(h[2], 0.f)), 0x07060302u);
        int off = (r * 512 + c0 * 2) ^ ((r & 7) << 4);
        *(uint2*)((char*)h0s[0] + off) = make_uint2(qlo, qhi);
    }
    __syncthreads();

    for (int t = 0; t < ITERS; ++t) {
        const int sb = t & 1;
        const int ib = t & 3;

        // out-write for tile t-1
        if (t > 0 && tid < TILE_M) {
            const int pb = sb ^ 1;
            float s = red[pb][0][tid] + red[pb][1][tid] + red[pb][2][tid] + red[pb][3][tid]
                    + red[pb][4][tid] + red[pb][5][tid] + red[pb][6][tid] + red[pb][7][tid];
            if (!MLP) s += b20;
            outp[(bid + (t - 1) * GRID_MLP) * TILE_M + tid] = s;
        }

        // MFMA(t) <- h0s[sb]
        f32x4 acc[2][2];
        {
            f32x4 bi0 = *(const f32x4*)&sh_b1[w * 32 + 4 * rg];
            f32x4 bi1 = *(const f32x4*)&sh_b1[w * 32 + 16 + 4 * rg];
            acc[0][0] = bi0; acc[1][0] = bi0;
            acc[0][1] = bi1; acc[1][1] = bi1;
        }
#pragma unroll
        for (int kk = 0; kk < 8; ++kk) {
#pragma unroll
            for (int rt = 0; rt < 2; ++rt) {
                int row = rt * 16 + arow;
                int off = (row * 512 + kk * 64 + rg * 16) ^ ((row & 7) << 4);
                bf16x8 hf = *(const bf16x8*)((const char*)h0s[sb] + off);
                acc[rt][0] = __builtin_amdgcn_mfma_f32_16x16x32_bf16(afrag[kk][0], hf, acc[rt][0], 0, 0, 0);
                acc[rt][1] = __builtin_amdgcn_mfma_f32_16x16x32_bf16(afrag[kk][1], hf, acc[rt][1], 0, 0, 0);
            }
        }
        // epilogue -> red[sb] (dW and bias folded here; out-write needs only red)
        float A0[2] = {0.f, 0.f}, A1[2] = {0.f, 0.f};
#pragma unroll
        for (int p = 0; p < 2; ++p) {
            f32x4 w20v = *(const f32x4*)&sh_w20[w * 32 + p * 16 + 4 * rg];
            f32x4 w21v = *(const f32x4*)&sh_w21[w * 32 + p * 16 + 4 * rg];
#pragma unroll
            for (int rt = 0; rt < 2; ++rt) {
#pragma unroll
                for (int i = 0; i < 4; ++i) {
                    float v = fmaxf(acc[rt][p][i], 0.f);
                    A0[rt] = fmaf(v, w20v[i], A0[rt]);
                    if (MLP) A1[rt] = fmaf(v, w21v[i], A1[rt]);
                }
            }
        }
#pragma unroll
        for (int rt = 0; rt < 2; ++rt) {
            A0[rt] += __shfl_xor(A0[rt], 16); A0[rt] += __shfl_xor(A0[rt], 32);
            if (MLP) { A1[rt] += __shfl_xor(A1[rt], 16); A1[rt] += __shfl_xor(A1[rt], 32); }
            if (rg == 0) {
                int row = rt * 16 + arow;
                float rv;
                if (MLP) {
                    float d0 = dws0[ib][row], d1 = dws1[ib][row];
                    rv = fmaf(A1[rt], d1, A0[rt] * d0);
                    if (w == 0) rv += fmaf(b21, d1, b20 * d0);
                } else {
                    rv = A0[rt];
                }
                red[sb][w][row] = rv;
            }
        }

        // layer0(t+1) <- scal[(t+1)&3] -> h0s[sb^1]
        if (t + 1 < ITERS) {
            const int jb = (t + 1) & 3;
#pragma unroll
            for (int ii = 0; ii < 4; ++ii) {
                int r = row0 + ii;
                float tv = tss[jb][r], x1 = txs1[jb][r], x2 = txs2[jb][r];
                f32x4 h;
#pragma unroll
                for (int j = 0; j < 4; ++j)
                    h[j] = fmaf(tv, w0t[j], fmaf(x1, w0x[j], fmaf(x2, w0y[j], w0bv[j])));
                unsigned qlo = __builtin_amdgcn_perm(__float_as_uint(fmaxf(h[1], 0.f)),
                                                     __float_as_uint(fmaxf(h[0], 0.f)), 0x07060302u);
                unsigned qhi = __builtin_amdgcn_perm(__float_as_uint(fmaxf(h[3], 0.f)),
                                                     __float_as_uint(fmaxf(h[2], 0.f)), 0x07060302u);
                int off = (r * 512 + c0 * 2) ^ ((r & 7) << 4);
                *(uint2*)((char*)h0s[sb ^ 1] + off) = make_uint2(qlo, qhi);
            }
        }
        // scal[(t+2)&3] <- prefetch regs ; then prefetch tile t+3
        if (tid < TILE_M) {
            if (t + 2 < ITERS) {
                const int kb = (t + 2) & 3;
                tss[kb][tid] = p_t; txs1[kb][tid] = p_x1; txs2[kb][tid] = p_x2;
                if (MLP) {
                    float sdt = sqrtf(p_tn - p_t);
                    dws0[kb][tid] = p_e0 * sdt; dws1[kb][tid] = p_e1 * sdt;
                }
            }
            if (t + 3 < ITERS) {
                int r = (bid + (t + 3) * GRID_MLP) * TILE_M + tid, n = r & (N_ - 1);
                float2 xv = ((const float2*)xs)[r];
                p_x1 = xv.x; p_x2 = xv.y;
                p_t = ts[n]; p_tn = (n < N_ - 1) ? ts[n + 1] : ts[n];
                if (MLP) { float2 ev = ((const float2*)eps)[r]; p_e0 = ev.x; p_e1 = ev.y; }
            }
        }
        __syncthreads();   // the single per-tile barrier
    }
    // final out-write (tile ITERS-1)
    if (tid < TILE_M) {
        const int pb = (ITERS - 1) & 1;
        float s = red[pb][0][tid] + red[pb][1][tid] + red[pb][2][tid] + red[pb][3][tid]
                + red[pb][4][tid] + red[pb][5][tid] + red[pb][6][tid] + red[pb][7][tid];
        if (!MLP) s += b20;
        outp[(bid + (ITERS - 1) * GRID_MLP) * TILE_M + tid] = s;
    }
}

// ---- loss: sum over r of (Y + Zdot - target)^2, /B ----
__global__ void loss_partial_kernel(const float* __restrict__ Yout, const float* __restrict__ fv,
                                    const float* __restrict__ zdot, float* __restrict__ partials) {
    __shared__ float wred[4];
    int tid = threadIdx.x;
    float s = 0.f;
    for (int r = blockIdx.x * 256 + tid; r < R_; r += gridDim.x * 256) {
        int n = r & (N_ - 1);
        float pred = Yout[r] + zdot[r];
        float target = (n == N_ - 1) ? fv[r >> 8] : Yout[r + 1];
        float d = pred - target;
        s = fmaf(d, d, s);
    }
#pragma unroll
    for (int m = 1; m < 64; m <<= 1) s += __shfl_xor(s, m);
    if ((tid & 63) == 0) wred[tid >> 6] = s;
    __syncthreads();
    if (tid == 0) partials[blockIdx.x] = wred[0] + wred[1] + wred[2] + wred[3];
}

__global__ void loss_final_kernel(const float* __restrict__ partials, float* __restrict__ out) {
    __shared__ float wred[4];
    int tid = threadIdx.x;
    float s = partials[tid] + partials[256 + tid] + partials[512 + tid] + partials[768 + tid];
#pragma unroll
    for (int m = 1; m < 64; m <<= 1) s += __shfl_xor(s, m);
    if ((tid & 63) == 0) wred[tid >> 6] = s;
    __syncthreads();
    if (tid == 0) out[0] = (wred[0] + wred[1] + wred[2] + wred[3]) * (1.0f / B_);
}

extern "C" void kernel_launch(void* const* d_in, const int* in_sizes, int n_in,
                              void* d_out, int out_size, void* d_ws, size_t ws_size,
                              hipStream_t stream) {
    const float* ts  = (const float*)d_in[0];
    const float* x0  = (const float*)d_in[1];
    const float* eps = (const float*)d_in[2];
    const float* fW0 = (const float*)d_in[3];
    const float* fb0 = (const float*)d_in[4];
    const float* fW1 = (const float*)d_in[5];
    const float* fb1 = (const float*)d_in[6];
    const float* fW2 = (const float*)d_in[7];
    const float* fb2 = (const float*)d_in[8];
    const float* gW0 = (const float*)d_in[9];
    const float* gb0 = (const float*)d_in[10];
    const float* gW1 = (const float*)d_in[11];
    const float* gb1 = (const float*)d_in[12];
    const float* gW2 = (const float*)d_in[13];
    const float* gb2 = (const float*)d_in[14];

    float* out  = (float*)d_out;
    float* Yout = out + 1;            // Y: (B,N,1) flat, row index r = b*N+n
    float* fv   = out + 1 + R_;       // final_value: (B,1)

    char* wsb = (char*)d_ws;
    float* xs            = (float*)wsb;                                         // B*N*2 f32 = 4MB
    unsigned short* wswz = (unsigned short*)(wsb + (4 << 20));                  // 256KB
    float* zdot          = (float*)(wsb + (4 << 20) + (256 << 10));             // 2MB
    float* partials      = (float*)(wsb + (4 << 20) + (256 << 10) + (2 << 20)); // 4KB

    hipLaunchKernelGGL(prep_weights, dim3(512), dim3(256), 0, stream, fW1, gW1, wswz);
    hipLaunchKernelGGL(traj_kernel, dim3(512), dim3(256), 0, stream, ts, x0, eps, xs, fv);
    hipLaunchKernelGGL(mlp_kernel, dim3(2 * GRID_MLP), dim3(512), 0, stream,
                       ts, eps, xs, wswz,
                       fW0, fb0, fb1, fW2, fb2,
                       gW0, gb0, gb1, gW2, gb2, Yout, zdot);
    hipLaunchKernelGGL(loss_partial_kernel, dim3(1024), dim3(256), 0, stream, Yout, fv, zdot, partials);
    hipLaunchKernelGGL(loss_final_kernel, dim3(1), dim3(256), 0, stream, partials, out);
}

// Round 10
// 217.833 us; speedup vs baseline: 1.0495x; 1.0495x over previous
//
#include <hip/hip_runtime.h>
#include <math.h>

#define B_ 2048
#define N_ 256
#define R_ (B_*N_)
#define MU_ 0.1f
#define SIGMA_ 0.2f
#define TILE_M 32
#define GRID_MLP 512
#define ITERS (R_ / TILE_M / GRID_MLP)   // 32

typedef __attribute__((ext_vector_type(4))) float f32x4;

// ---- convert fW1/gW1 (256x256 f32, k-major) to fp8-e4m3 MFMA fragments ----
// byte idx = ((kk*16 + ct)*64 + lane)*8 + j ; holds W1[k = kk*32+(lane>>4)*8+j][c = ct*16+(lane&15)]
// (A and B frags use the same (group,j)->k map, so any HW-internal k permutation cancels)
__global__ void prep_weights(const float* __restrict__ fW1, const float* __restrict__ gW1,
                             unsigned int* __restrict__ wswz) {
    int idx = blockIdx.x * 256 + threadIdx.x;   // u32-word index, 16384 words per MLP
    if (idx >= 2 * 16384) return;
    int m = idx >> 14, wi = idx & 16383;
    int frag = wi >> 7;                 // kk*16 + ct
    int w2 = wi & 127;
    int lane = w2 >> 1, q = w2 & 1;     // q: low/high 4 bytes of the 8-byte lane block
    int kk = frag >> 4, ct = frag & 15;
    int kb = kk * 32 + (lane >> 4) * 8 + q * 4;
    int c = ct * 16 + (lane & 15);
    const float* W = m ? gW1 : fW1;
    float v0 = W[(kb + 0) * 256 + c];
    float v1 = W[(kb + 1) * 256 + c];
    float v2 = W[(kb + 2) * 256 + c];
    float v3 = W[(kb + 3) * 256 + c];
    int u = __builtin_amdgcn_cvt_pk_fp8_f32(v0, v1, 0, false);
    u = __builtin_amdgcn_cvt_pk_fp8_f32(v2, v3, u, true);
    wswz[idx] = (unsigned int)u;
}

// ---- trajectory via wave-parallel prefix-product scan: one wave per batch row ----
__global__ void traj_kernel(const float* __restrict__ ts, const float* __restrict__ x0,
                            const float* __restrict__ eps, float* __restrict__ xs,
                            float* __restrict__ fv) {
    int gid = blockIdx.x * 256 + threadIdx.x;
    int b = gid >> 6, lane = gid & 63;
    int n0 = lane * 4;

    float t0 = ts[n0], t1 = ts[n0 + 1], t2 = ts[n0 + 2], t3 = ts[n0 + 3];
    float t4 = (n0 + 4 < N_) ? ts[n0 + 4] : t3;          // lane 63: h3 = 0
    float h0 = t1 - t0, h1 = t2 - t1, h2 = t3 - t2, h3 = t4 - t3;
    float s0 = sqrtf(h0), s1 = sqrtf(h1), s2 = sqrtf(h2), s3 = sqrtf(h3);

    const float4* e4 = (const float4*)(eps + (size_t)(b * N_ + n0) * 2);
    float4 ea = e4[0], eb = e4[1];
    float f0a = 1.f + MU_ * h0 + SIGMA_ * (ea.x * s0);
    float f0b = 1.f + MU_ * h0 + SIGMA_ * (ea.y * s0);
    float f1a = 1.f + MU_ * h1 + SIGMA_ * (ea.z * s1);
    float f1b = 1.f + MU_ * h1 + SIGMA_ * (ea.w * s1);
    float f2a = 1.f + MU_ * h2 + SIGMA_ * (eb.x * s2);
    float f2b = 1.f + MU_ * h2 + SIGMA_ * (eb.y * s2);
    float f3a = 1.f + MU_ * h3 + SIGMA_ * (eb.z * s3);
    float f3b = 1.f + MU_ * h3 + SIGMA_ * (eb.w * s3);

    float Pa = f0a * f1a * f2a * f3a;
    float Pb = f0b * f1b * f2b * f3b;
    float Sa = Pa, Sb = Pb;
#pragma unroll
    for (int d = 1; d < 64; d <<= 1) {
        float va = __shfl_up(Sa, d);
        float vb = __shfl_up(Sb, d);
        if (lane >= d) { Sa *= va; Sb *= vb; }
    }
    float Ea = __shfl_up(Sa, 1);
    float Eb = __shfl_up(Sb, 1);
    if (lane == 0) { Ea = 1.f; Eb = 1.f; }

    float x0a = x0[2 * b], x0b = x0[2 * b + 1];
    float xa0 = x0a * Ea, xb0 = x0b * Eb;
    float xa1 = xa0 * f0a, xb1 = xb0 * f0b;
    float xa2 = xa1 * f1a, xb2 = xb1 * f1b;
    float xa3 = xa2 * f2a, xb3 = xb2 * f2b;

    float4* xsv = (float4*)(xs + (size_t)(b * N_ + n0) * 2);
    xsv[0] = make_float4(xa0, xb0, xa1, xb1);
    xsv[1] = make_float4(xa2, xb2, xa3, xb3);
    if (lane == 63) fv[b] = xa3 * xa3 + xb3 * xb3;
}

// ---- fused MLP, transposed GEMM in fp8: D = W1^T(A, resident regs) @ h0^T(B, LDS) ----
// Structure = round 9 (merged f+g, single barrier per tile); dtype change only:
//  - afrag: 8kk x 2ct x i64 = 32 VGPRs (was 64)
//  - h0s: fp8 bytes, 8KB/buffer (was 16KB); b64 reads (was b128) -> LDS traffic halved
//  - LDS/block ~24KB -> 2 blocks co-residable even under a 64KiB effective limit
__global__ __launch_bounds__(512) void mlp_kernel(
        const float* __restrict__ ts, const float* __restrict__ eps, const float* __restrict__ xs,
        const unsigned int* __restrict__ wswz,
        const float* __restrict__ fW0, const float* __restrict__ fb0,
        const float* __restrict__ fb1, const float* __restrict__ fW2, const float* __restrict__ fb2,
        const float* __restrict__ gW0, const float* __restrict__ gb0,
        const float* __restrict__ gb1, const float* __restrict__ gW2, const float* __restrict__ gb2,
        float* __restrict__ Yout, float* __restrict__ zdot) {

    __shared__ __align__(16) unsigned char h0s[2][TILE_M * 256];   // fp8, XOR-swizzled rows
    __shared__ float tss[4][TILE_M], txs1[4][TILE_M], txs2[4][TILE_M];
    __shared__ float dws0[4][TILE_M], dws1[4][TILE_M];
    __shared__ float red[2][8][TILE_M];
    __shared__ __align__(16) float sh_b1[256], sh_w20[256], sh_w21[256];

    const int MLP = blockIdx.x & 1;
    const int bid = blockIdx.x >> 1;

    const float* W0 = MLP ? gW0 : fW0;
    const float* b0 = MLP ? gb0 : fb0;
    const float* b1 = MLP ? gb1 : fb1;
    const float* W2 = MLP ? gW2 : fW2;
    const float* b2 = MLP ? gb2 : fb2;
    float* outp     = MLP ? zdot : Yout;

    const int tid  = threadIdx.x;
    const int lane = tid & 63;
    const int w    = tid >> 6;       // wave 0..7: cols [32w, 32w+32)
    const int arow = lane & 15;      // sample index within 16-tile
    const int rg   = lane >> 4;      // k-group / c-subgroup

    const int c0 = (tid & 63) * 4;   // layer0 col base
    const int row0 = (tid >> 6) * 4; // layer0 row base
    f32x4 w0t = *(const f32x4*)(W0 + c0);
    f32x4 w0x = *(const f32x4*)(W0 + 256 + c0);
    f32x4 w0y = *(const f32x4*)(W0 + 512 + c0);
    f32x4 w0bv = *(const f32x4*)(b0 + c0);

    if (tid < 256) {
        sh_b1[tid] = b1[tid];
        if (MLP) { sh_w20[tid] = W2[2 * tid]; sh_w21[tid] = W2[2 * tid + 1]; }
        else     { sh_w20[tid] = W2[tid];     sh_w21[tid] = 0.f; }
    }
    const float b20 = b2[0];
    const float b21 = MLP ? b2[1] : 0.f;

    // resident A-fragments of W1^T (fp8): 8 kk x 2 ct x i64 = 32 VGPRs
    long afrag[8][2];
    const long* wsw8 = (const long*)(wswz + MLP * 16384);
#pragma unroll
    for (int kk = 0; kk < 8; ++kk)
#pragma unroll
        for (int p = 0; p < 2; ++p)
            afrag[kk][p] = wsw8[(kk * 16 + (w * 2 + p)) * 64 + lane];

    // prologue: stage tiles 0,1 -> scal[0],scal[1]; prefetch tile 2 -> regs
    float p_x1 = 0.f, p_x2 = 0.f, p_t = 0.f, p_tn = 0.f, p_e0 = 0.f, p_e1 = 0.f;
    if (tid < TILE_M) {
#pragma unroll
        for (int tt = 0; tt < 2; ++tt) {
            int r = (bid + tt * GRID_MLP) * TILE_M + tid, n = r & (N_ - 1);
            float2 xv = ((const float2*)xs)[r];
            float tv = ts[n];
            tss[tt][tid] = tv; txs1[tt][tid] = xv.x; txs2[tt][tid] = xv.y;
            if (MLP) {
                float tn = (n < N_ - 1) ? ts[n + 1] : tv;
                float sdt = sqrtf(tn - tv);
                float2 ev = ((const float2*)eps)[r];
                dws0[tt][tid] = ev.x * sdt; dws1[tt][tid] = ev.y * sdt;
            }
        }
        int r = (bid + 2 * GRID_MLP) * TILE_M + tid, n = r & (N_ - 1);
        float2 xv = ((const float2*)xs)[r];
        p_x1 = xv.x; p_x2 = xv.y;
        p_t = ts[n]; p_tn = (n < N_ - 1) ? ts[n + 1] : ts[n];
        if (MLP) { float2 ev = ((const float2*)eps)[r]; p_e0 = ev.x; p_e1 = ev.y; }
    }
    __syncthreads();
    // layer0 tile 0 -> h0s[0] (fp8 pack: 4 cols -> 1 u32)
#pragma unroll
    for (int ii = 0; ii < 4; ++ii) {
        int r = row0 + ii;
        float t = tss[0][r], x1 = txs1[0][r], x2 = txs2[0][r];
        f32x4 h;
#pragma unroll
        for (int j = 0; j < 4; ++j)
            h[j] = fmaxf(fmaf(t, w0t[j], fmaf(x1, w0x[j], fmaf(x2, w0y[j], w0bv[j]))), 0.f);
        int q = __builtin_amdgcn_cvt_pk_fp8_f32(h[0], h[1], 0, false);
        q = __builtin_amdgcn_cvt_pk_fp8_f32(h[2], h[3], q, true);
        int off = r * 256 + (c0 ^ ((r & 15) << 3));
        *(unsigned int*)(h0s[0] + off) = (unsigned int)q;
    }
    __syncthreads();

    for (int t = 0; t < ITERS; ++t) {
        const int sb = t & 1;
        const int ib = t & 3;

        // out-write for tile t-1
        if (t > 0 && tid < TILE_M) {
            const int pb = sb ^ 1;
            float s = red[pb][0][tid] + red[pb][1][tid] + red[pb][2][tid] + red[pb][3][tid]
                    + red[pb][4][tid] + red[pb][5][tid] + red[pb][6][tid] + red[pb][7][tid];
            if (!MLP) s += b20;
            outp[(bid + (t - 1) * GRID_MLP) * TILE_M + tid] = s;
        }

        // MFMA(t) <- h0s[sb]  (fp8: b64 reads, bank-balanced swizzle)
        f32x4 acc[2][2];
        {
            f32x4 bi0 = *(const f32x4*)&sh_b1[w * 32 + 4 * rg];
            f32x4 bi1 = *(const f32x4*)&sh_b1[w * 32 + 16 + 4 * rg];
            acc[0][0] = bi0; acc[1][0] = bi0;
            acc[0][1] = bi1; acc[1][1] = bi1;
        }
#pragma unroll
        for (int kk = 0; kk < 8; ++kk) {
#pragma unroll
            for (int rt = 0; rt < 2; ++rt) {
                int row = rt * 16 + arow;
                int off = row * 256 + ((kk * 32 + rg * 8) ^ ((row & 15) << 3));
                long hf = *(const long*)(h0s[sb] + off);
                acc[rt][0] = __builtin_amdgcn_mfma_f32_16x16x32_fp8_fp8(afrag[kk][0], hf, acc[rt][0], 0, 0, 0);
                acc[rt][1] = __builtin_amdgcn_mfma_f32_16x16x32_fp8_fp8(afrag[kk][1], hf, acc[rt][1], 0, 0, 0);
            }
        }
        // epilogue -> red[sb] (dW and bias folded here; out-write needs only red)
        float A0[2] = {0.f, 0.f}, A1[2] = {0.f, 0.f};
#pragma unroll
        for (int p = 0; p < 2; ++p) {
            f32x4 w20v = *(const f32x4*)&sh_w20[w * 32 + p * 16 + 4 * rg];
            f32x4 w21v = *(const f32x4*)&sh_w21[w * 32 + p * 16 + 4 * rg];
#pragma unroll
            for (int rt = 0; rt < 2; ++rt) {
#pragma unroll
                for (int i = 0; i < 4; ++i) {
                    float v = fmaxf(acc[rt][p][i], 0.f);
                    A0[rt] = fmaf(v, w20v[i], A0[rt]);
                    if (MLP) A1[rt] = fmaf(v, w21v[i], A1[rt]);
                }
            }
        }
#pragma unroll
        for (int rt = 0; rt < 2; ++rt) {
            A0[rt] += __shfl_xor(A0[rt], 16); A0[rt] += __shfl_xor(A0[rt], 32);
            if (MLP) { A1[rt] += __shfl_xor(A1[rt], 16); A1[rt] += __shfl_xor(A1[rt], 32); }
            if (rg == 0) {
                int row = rt * 16 + arow;
                float rv;
                if (MLP) {
                    float d0 = dws0[ib][row], d1 = dws1[ib][row];
                    rv = fmaf(A1[rt], d1, A0[rt] * d0);
                    if (w == 0) rv += fmaf(b21, d1, b20 * d0);
                } else {
                    rv = A0[rt];
                }
                red[sb][w][row] = rv;
            }
        }

        // layer0(t+1) <- scal[(t+1)&3] -> h0s[sb^1]
        if (t + 1 < ITERS) {
            const int jb = (t + 1) & 3;
#pragma unroll
            for (int ii = 0; ii < 4; ++ii) {
                int r = row0 + ii;
                float tv = tss[jb][r], x1 = txs1[jb][r], x2 = txs2[jb][r];
                f32x4 h;
#pragma unroll
                for (int j = 0; j < 4; ++j)
                    h[j] = fmaxf(fmaf(tv, w0t[j], fmaf(x1, w0x[j], fmaf(x2, w0y[j], w0bv[j]))), 0.f);
                int q = __builtin_amdgcn_cvt_pk_fp8_f32(h[0], h[1], 0, false);
                q = __builtin_amdgcn_cvt_pk_fp8_f32(h[2], h[3], q, true);
                int off = r * 256 + (c0 ^ ((r & 15) << 3));
                *(unsigned int*)(h0s[sb ^ 1] + off) = (unsigned int)q;
            }
        }
        // scal[(t+2)&3] <- prefetch regs ; then prefetch tile t+3
        if (tid < TILE_M) {
            if (t + 2 < ITERS) {
                const int kb = (t + 2) & 3;
                tss[kb][tid] = p_t; txs1[kb][tid] = p_x1; txs2[kb][tid] = p_x2;
                if (MLP) {
                    float sdt = sqrtf(p_tn - p_t);
                    dws0[kb][tid] = p_e0 * sdt; dws1[kb][tid] = p_e1 * sdt;
                }
            }
            if (t + 3 < ITERS) {
                int r = (bid + (t + 3) * GRID_MLP) * TILE_M + tid, n = r & (N_ - 1);
                float2 xv = ((const float2*)xs)[r];
                p_x1 = xv.x; p_x2 = xv.y;
                p_t = ts[n]; p_tn = (n < N_ - 1) ? ts[n + 1] : ts[n];
                if (MLP) { float2 ev = ((const float2*)eps)[r]; p_e0 = ev.x; p_e1 = ev.y; }
            }
        }
        __syncthreads();   // the single per-tile barrier
    }
    // final out-write (tile ITERS-1)
    if (tid < TILE_M) {
        const int pb = (ITERS - 1) & 1;
        float s = red[pb][0][tid] + red[pb][1][tid] + red[pb][2][tid] + red[pb][3][tid]
                + red[pb][4][tid] + red[pb][5][tid] + red[pb][6][tid] + red[pb][7][tid];
        if (!MLP) s += b20;
        outp[(bid + (ITERS - 1) * GRID_MLP) * TILE_M + tid] = s;
    }
}

// ---- loss: sum over r of (Y + Zdot - target)^2, /B ----
__global__ void loss_partial_kernel(const float* __restrict__ Yout, const float* __restrict__ fv,
                                    const float* __restrict__ zdot, float* __restrict__ partials) {
    __shared__ float wred[4];
    int tid = threadIdx.x;
    float s = 0.f;
    for (int r = blockIdx.x * 256 + tid; r < R_; r += gridDim.x * 256) {
        int n = r & (N_ - 1);
        float pred = Yout[r] + zdot[r];
        float target = (n == N_ - 1) ? fv[r >> 8] : Yout[r + 1];
        float d = pred - target;
        s = fmaf(d, d, s);
    }
#pragma unroll
    for (int m = 1; m < 64; m <<= 1) s += __shfl_xor(s, m);
    if ((tid & 63) == 0) wred[tid >> 6] = s;
    __syncthreads();
    if (tid == 0) partials[blockIdx.x] = wred[0] + wred[1] + wred[2] + wred[3];
}

__global__ void loss_final_kernel(const float* __restrict__ partials, float* __restrict__ out) {
    __shared__ float wred[4];
    int tid = threadIdx.x;
    float s = partials[tid] + partials[256 + tid] + partials[512 + tid] + partials[768 + tid];
#pragma unroll
    for (int m = 1; m < 64; m <<= 1) s += __shfl_xor(s, m);
    if ((tid & 63) == 0) wred[tid >> 6] = s;
    __syncthreads();
    if (tid == 0) out[0] = (wred[0] + wred[1] + wred[2] + wred[3]) * (1.0f / B_);
}

extern "C" void kernel_launch(void* const* d_in, const int* in_sizes, int n_in,
                              void* d_out, int out_size, void* d_ws, size_t ws_size,
                              hipStream_t stream) {
    const float* ts  = (const float*)d_in[0];
    const float* x0  = (const float*)d_in[1];
    const float* eps = (const float*)d_in[2];
    const float* fW0 = (const float*)d_in[3];
    const float* fb0 = (const float*)d_in[4];
    const float* fW1 = (const float*)d_in[5];
    const float* fb1 = (const float*)d_in[6];
    const float* fW2 = (const float*)d_in[7];
    const float* fb2 = (const float*)d_in[8];
    const float* gW0 = (const float*)d_in[9];
    const float* gb0 = (const float*)d_in[10];
    const float* gW1 = (const float*)d_in[11];
    const float* gb1 = (const float*)d_in[12];
    const float* gW2 = (const float*)d_in[13];
    const float* gb2 = (const float*)d_in[14];

    float* out  = (float*)d_out;
    float* Yout = out + 1;            // Y: (B,N,1) flat, row index r = b*N+n
    float* fv   = out + 1 + R_;       // final_value: (B,1)

    char* wsb = (char*)d_ws;
    float* xs           = (float*)wsb;                                          // B*N*2 f32 = 4MB
    unsigned int* wswz  = (unsigned int*)(wsb + (4 << 20));                     // fp8 frags, 128KB
    float* zdot         = (float*)(wsb + (4 << 20) + (256 << 10));              // 2MB
    float* partials     = (float*)(wsb + (4 << 20) + (256 << 10) + (2 << 20));  // 4KB

    hipLaunchKernelGGL(prep_weights, dim3(128), dim3(256), 0, stream, fW1, gW1, wswz);
    hipLaunchKernelGGL(traj_kernel, dim3(512), dim3(256), 0, stream, ts, x0, eps, xs, fv);
    hipLaunchKernelGGL(mlp_kernel, dim3(2 * GRID_MLP), dim3(512), 0, stream,
                       ts, eps, xs, wswz,
                       fW0, fb0, fb1, fW2, fb2,
                       gW0, gb0, gb1, gW2, gb2, Yout, zdot);
    hipLaunchKernelGGL(loss_partial_kernel, dim3(1024), dim3(256), 0, stream, Yout, fv, zdot, partials);
    hipLaunchKernelGGL(loss_final_kernel, dim3(1), dim3(256), 0, stream, partials, out);
}

// Round 11
// 193.716 us; speedup vs baseline: 1.1802x; 1.1245x over previous
//
#include <hip/hip_runtime.h>
#include <math.h>

#define B_ 2048
#define N_ 256
#define R_ (B_*N_)
#define MU_ 0.1f
#define SIGMA_ 0.2f
#define TILE_M 64
#define GRID_MLP 512
#define ITERS (R_ / TILE_M / GRID_MLP)   // 16

typedef __attribute__((ext_vector_type(4))) float f32x4;

// ---- convert fW1/gW1 (256x256 f32, k-major) to fp8-e4m3 MFMA fragments ----
// byte idx = ((kk*16 + ct)*64 + lane)*8 + j ; holds W1[k = kk*32+(lane>>4)*8+j][c = ct*16+(lane&15)]
__global__ void prep_weights(const float* __restrict__ fW1, const float* __restrict__ gW1,
                             unsigned int* __restrict__ wswz) {
    int idx = blockIdx.x * 256 + threadIdx.x;   // u32-word index, 16384 words per MLP
    if (idx >= 2 * 16384) return;
    int m = idx >> 14, wi = idx & 16383;
    int frag = wi >> 7;                 // kk*16 + ct
    int w2 = wi & 127;
    int lane = w2 >> 1, q = w2 & 1;
    int kk = frag >> 4, ct = frag & 15;
    int kb = kk * 32 + (lane >> 4) * 8 + q * 4;
    int c = ct * 16 + (lane & 15);
    const float* W = m ? gW1 : fW1;
    float v0 = W[(kb + 0) * 256 + c];
    float v1 = W[(kb + 1) * 256 + c];
    float v2 = W[(kb + 2) * 256 + c];
    float v3 = W[(kb + 3) * 256 + c];
    int u = __builtin_amdgcn_cvt_pk_fp8_f32(v0, v1, 0, false);
    u = __builtin_amdgcn_cvt_pk_fp8_f32(v2, v3, u, true);
    wswz[idx] = (unsigned int)u;
}

// ---- trajectory via wave-parallel prefix-product scan: one wave per batch row ----
__global__ void traj_kernel(const float* __restrict__ ts, const float* __restrict__ x0,
                            const float* __restrict__ eps, float* __restrict__ xs,
                            float* __restrict__ fv) {
    int gid = blockIdx.x * 256 + threadIdx.x;
    int b = gid >> 6, lane = gid & 63;
    int n0 = lane * 4;

    float t0 = ts[n0], t1 = ts[n0 + 1], t2 = ts[n0 + 2], t3 = ts[n0 + 3];
    float t4 = (n0 + 4 < N_) ? ts[n0 + 4] : t3;          // lane 63: h3 = 0
    float h0 = t1 - t0, h1 = t2 - t1, h2 = t3 - t2, h3 = t4 - t3;
    float s0 = sqrtf(h0), s1 = sqrtf(h1), s2 = sqrtf(h2), s3 = sqrtf(h3);

    const float4* e4 = (const float4*)(eps + (size_t)(b * N_ + n0) * 2);
    float4 ea = e4[0], eb = e4[1];
    float f0a = 1.f + MU_ * h0 + SIGMA_ * (ea.x * s0);
    float f0b = 1.f + MU_ * h0 + SIGMA_ * (ea.y * s0);
    float f1a = 1.f + MU_ * h1 + SIGMA_ * (ea.z * s1);
    float f1b = 1.f + MU_ * h1 + SIGMA_ * (ea.w * s1);
    float f2a = 1.f + MU_ * h2 + SIGMA_ * (eb.x * s2);
    float f2b = 1.f + MU_ * h2 + SIGMA_ * (eb.y * s2);
    float f3a = 1.f + MU_ * h3 + SIGMA_ * (eb.z * s3);
    float f3b = 1.f + MU_ * h3 + SIGMA_ * (eb.w * s3);

    float Pa = f0a * f1a * f2a * f3a;
    float Pb = f0b * f1b * f2b * f3b;
    float Sa = Pa, Sb = Pb;
#pragma unroll
    for (int d = 1; d < 64; d <<= 1) {
        float va = __shfl_up(Sa, d);
        float vb = __shfl_up(Sb, d);
        if (lane >= d) { Sa *= va; Sb *= vb; }
    }
    float Ea = __shfl_up(Sa, 1);
    float Eb = __shfl_up(Sb, 1);
    if (lane == 0) { Ea = 1.f; Eb = 1.f; }

    float x0a = x0[2 * b], x0b = x0[2 * b + 1];
    float xa0 = x0a * Ea, xb0 = x0b * Eb;
    float xa1 = xa0 * f0a, xb1 = xb0 * f0b;
    float xa2 = xa1 * f1a, xb2 = xb1 * f1b;
    float xa3 = xa2 * f2a, xb3 = xb2 * f2b;

    float4* xsv = (float4*)(xs + (size_t)(b * N_ + n0) * 2);
    xsv[0] = make_float4(xa0, xb0, xa1, xb1);
    xsv[1] = make_float4(xa2, xb2, xa3, xb3);
    if (lane == 63) fv[b] = xa3 * xa3 + xb3 * xb3;
}

// ---- fused MLP, fp8 transposed GEMM, LDS-resident samples ----
// Merged f+g: grid 1024, MLP=blockIdx&1, bid=blockIdx>>1. TILE_M=64, ITERS=16.
// ALL sample data (1024 samples x {t,x1,x2,d0,d1}) preloaded to LDS once ->
// zero in-loop global loads -> the per-barrier vmcnt(0) drain no longer exposes
// HBM latency 128x/CU (r10 diagnosis). Fat phases: 64 MFMA/wave/tile, 8 acc chains.
__global__ __launch_bounds__(512) void mlp_kernel(
        const float* __restrict__ ts, const float* __restrict__ eps, const float* __restrict__ xs,
        const unsigned int* __restrict__ wswz,
        const float* __restrict__ fW0, const float* __restrict__ fb0,
        const float* __restrict__ fb1, const float* __restrict__ fW2, const float* __restrict__ fb2,
        const float* __restrict__ gW0, const float* __restrict__ gb0,
        const float* __restrict__ gb1, const float* __restrict__ gW2, const float* __restrict__ gb2,
        float* __restrict__ Yout, float* __restrict__ zdot) {

    __shared__ __align__(16) unsigned char h0s[2][TILE_M * 256];   // fp8, 2 x 16KB, XOR-swizzled
    __shared__ float st[TILE_M * ITERS], sx1[TILE_M * ITERS], sx2[TILE_M * ITERS];
    __shared__ float sd0[TILE_M * ITERS], sd1[TILE_M * ITERS];
    __shared__ float red[2][8][TILE_M];
    __shared__ __align__(16) float sh_b1[256], sh_w20[256], sh_w21[256];

    const int MLP = blockIdx.x & 1;
    const int bid = blockIdx.x >> 1;

    const float* W0 = MLP ? gW0 : fW0;
    const float* b0 = MLP ? gb0 : fb0;
    const float* b1 = MLP ? gb1 : fb1;
    const float* W2 = MLP ? gW2 : fW2;
    const float* b2 = MLP ? gb2 : fb2;
    float* outp     = MLP ? zdot : Yout;

    const int tid  = threadIdx.x;
    const int lane = tid & 63;
    const int w    = tid >> 6;       // wave 0..7: cols [32w, 32w+32)
    const int arow = lane & 15;      // sample index within 16-row tile
    const int rg   = lane >> 4;      // k-group / c-subgroup

    const int c0 = (tid & 63) * 4;   // layer0 col base
    const int row0 = (tid >> 6) * 8; // layer0 row base (8 rows/thread)
    f32x4 w0t = *(const f32x4*)(W0 + c0);
    f32x4 w0x = *(const f32x4*)(W0 + 256 + c0);
    f32x4 w0y = *(const f32x4*)(W0 + 512 + c0);
    f32x4 w0bv = *(const f32x4*)(b0 + c0);

    if (tid < 256) {
        sh_b1[tid] = b1[tid];
        if (MLP) { sh_w20[tid] = W2[2 * tid]; sh_w21[tid] = W2[2 * tid + 1]; }
        else     { sh_w20[tid] = W2[tid];     sh_w21[tid] = 0.f; }
    }
    const float b20 = b2[0];
    const float b21 = MLP ? b2[1] : 0.f;

    // resident A-fragments of W1^T (fp8): 8 kk x 2 ct x i64 = 32 VGPRs
    long afrag[8][2];
    const long* wsw8 = (const long*)(wswz + MLP * 16384);
#pragma unroll
    for (int kk = 0; kk < 8; ++kk)
#pragma unroll
        for (int p = 0; p < 2; ++p)
            afrag[kk][p] = wsw8[(kk * 16 + (w * 2 + p)) * 64 + lane];

    // ---- preload ALL per-block sample data to LDS (coalesced, once) ----
#pragma unroll
    for (int q = 0; q < 2; ++q) {
        int s = q * 512 + tid;                 // 0..1023
        int it = s >> 6, i = s & 63;
        int r = (bid + it * GRID_MLP) * TILE_M + i;
        int n = r & (N_ - 1);
        float2 xv = ((const float2*)xs)[r];
        float tv = ts[n];
        st[s] = tv; sx1[s] = xv.x; sx2[s] = xv.y;
        if (MLP) {
            float sdt = (n < N_ - 1) ? sqrtf(ts[n + 1] - tv) : 0.f;
            float2 ev = ((const float2*)eps)[r];
            sd0[s] = ev.x * sdt; sd1[s] = ev.y * sdt;
        }
    }
    __syncthreads();

    // layer0 tile 0 -> h0s[0]
#pragma unroll
    for (int ii = 0; ii < 8; ++ii) {
        int r = row0 + ii;
        float t = st[r], x1 = sx1[r], x2 = sx2[r];
        f32x4 h;
#pragma unroll
        for (int j = 0; j < 4; ++j)
            h[j] = fmaxf(fmaf(t, w0t[j], fmaf(x1, w0x[j], fmaf(x2, w0y[j], w0bv[j]))), 0.f);
        int q = __builtin_amdgcn_cvt_pk_fp8_f32(h[0], h[1], 0, false);
        q = __builtin_amdgcn_cvt_pk_fp8_f32(h[2], h[3], q, true);
        int off = r * 256 + (c0 ^ ((r & 15) << 3));
        *(unsigned int*)(h0s[0] + off) = (unsigned int)q;
    }
    __syncthreads();

    for (int t = 0; t < ITERS; ++t) {
        const int sb = t & 1;

        // out-write for tile t-1 (fire-and-forget store; only in-loop global op)
        if (t > 0 && tid < TILE_M) {
            const int pb = sb ^ 1;
            float s = red[pb][0][tid] + red[pb][1][tid] + red[pb][2][tid] + red[pb][3][tid]
                    + red[pb][4][tid] + red[pb][5][tid] + red[pb][6][tid] + red[pb][7][tid];
            if (!MLP) s += b20;
            outp[(bid + (t - 1) * GRID_MLP) * TILE_M + tid] = s;
        }

        // MFMA(t) <- h0s[sb]: 8 kk x 4 rt x 2 p = 64 MFMA, 8 independent acc chains
        f32x4 acc[4][2];
        {
            f32x4 bi0 = *(const f32x4*)&sh_b1[w * 32 + 4 * rg];
            f32x4 bi1 = *(const f32x4*)&sh_b1[w * 32 + 16 + 4 * rg];
#pragma unroll
            for (int rt = 0; rt < 4; ++rt) { acc[rt][0] = bi0; acc[rt][1] = bi1; }
        }
#pragma unroll
        for (int kk = 0; kk < 8; ++kk) {
#pragma unroll
            for (int rt = 0; rt < 4; ++rt) {
                int row = rt * 16 + arow;
                int off = row * 256 + ((kk * 32 + rg * 8) ^ ((row & 15) << 3));
                long hf = *(const long*)(h0s[sb] + off);
                acc[rt][0] = __builtin_amdgcn_mfma_f32_16x16x32_fp8_fp8(afrag[kk][0], hf, acc[rt][0], 0, 0, 0);
                acc[rt][1] = __builtin_amdgcn_mfma_f32_16x16x32_fp8_fp8(afrag[kk][1], hf, acc[rt][1], 0, 0, 0);
            }
        }

        // epilogue -> red[sb]
#pragma unroll
        for (int rt = 0; rt < 4; ++rt) {
            float A0 = 0.f, A1 = 0.f;
#pragma unroll
            for (int p = 0; p < 2; ++p) {
                f32x4 w20v = *(const f32x4*)&sh_w20[w * 32 + p * 16 + 4 * rg];
                f32x4 w21v = *(const f32x4*)&sh_w21[w * 32 + p * 16 + 4 * rg];
#pragma unroll
                for (int i = 0; i < 4; ++i) {
                    float v = fmaxf(acc[rt][p][i], 0.f);
                    A0 = fmaf(v, w20v[i], A0);
                    if (MLP) A1 = fmaf(v, w21v[i], A1);
                }
            }
            A0 += __shfl_xor(A0, 16); A0 += __shfl_xor(A0, 32);
            if (MLP) { A1 += __shfl_xor(A1, 16); A1 += __shfl_xor(A1, 32); }
            if (rg == 0) {
                int row = rt * 16 + arow;
                float rv;
                if (MLP) {
                    int s = t * TILE_M + row;
                    float d0 = sd0[s], d1 = sd1[s];
                    rv = fmaf(A1, d1, A0 * d0);
                    if (w == 0) rv += fmaf(b21, d1, b20 * d0);
                } else {
                    rv = A0;
                }
                red[sb][w][row] = rv;
            }
        }

        // layer0(t+1) -> h0s[sb^1] (reads LDS-resident samples only)
        if (t + 1 < ITERS) {
            const int sbase = (t + 1) * TILE_M;
#pragma unroll
            for (int ii = 0; ii < 8; ++ii) {
                int r = row0 + ii;
                int s = sbase + r;
                float tv = st[s], x1 = sx1[s], x2 = sx2[s];
                f32x4 h;
#pragma unroll
                for (int j = 0; j < 4; ++j)
                    h[j] = fmaxf(fmaf(tv, w0t[j], fmaf(x1, w0x[j], fmaf(x2, w0y[j], w0bv[j]))), 0.f);
                int q = __builtin_amdgcn_cvt_pk_fp8_f32(h[0], h[1], 0, false);
                q = __builtin_amdgcn_cvt_pk_fp8_f32(h[2], h[3], q, true);
                int off = r * 256 + (c0 ^ ((r & 15) << 3));
                *(unsigned int*)(h0s[sb ^ 1] + off) = (unsigned int)q;
            }
        }
        __syncthreads();   // single per-tile barrier (LDS-only drain now)
    }
    // final out-write (tile ITERS-1)
    if (tid < TILE_M) {
        const int pb = (ITERS - 1) & 1;
        float s = red[pb][0][tid] + red[pb][1][tid] + red[pb][2][tid] + red[pb][3][tid]
                + red[pb][4][tid] + red[pb][5][tid] + red[pb][6][tid] + red[pb][7][tid];
        if (!MLP) s += b20;
        outp[(bid + (ITERS - 1) * GRID_MLP) * TILE_M + tid] = s;
    }
}

// ---- loss: sum over r of (Y + Zdot - target)^2, /B ----
__global__ void loss_partial_kernel(const float* __restrict__ Yout, const float* __restrict__ fv,
                                    const float* __restrict__ zdot, float* __restrict__ partials) {
    __shared__ float wred[4];
    int tid = threadIdx.x;
    float s = 0.f;
    for (int r = blockIdx.x * 256 + tid; r < R_; r += gridDim.x * 256) {
        int n = r & (N_ - 1);
        float pred = Yout[r] + zdot[r];
        float target = (n == N_ - 1) ? fv[r >> 8] : Yout[r + 1];
        float d = pred - target;
        s = fmaf(d, d, s);
    }
#pragma unroll
    for (int m = 1; m < 64; m <<= 1) s += __shfl_xor(s, m);
    if ((tid & 63) == 0) wred[tid >> 6] = s;
    __syncthreads();
    if (tid == 0) partials[blockIdx.x] = wred[0] + wred[1] + wred[2] + wred[3];
}

__global__ void loss_final_kernel(const float* __restrict__ partials, float* __restrict__ out) {
    __shared__ float wred[4];
    int tid = threadIdx.x;
    float s = partials[tid] + partials[256 + tid] + partials[512 + tid] + partials[768 + tid];
#pragma unroll
    for (int m = 1; m < 64; m <<= 1) s += __shfl_xor(s, m);
    if ((tid & 63) == 0) wred[tid >> 6] = s;
    __syncthreads();
    if (tid == 0) out[0] = (wred[0] + wred[1] + wred[2] + wred[3]) * (1.0f / B_);
}

extern "C" void kernel_launch(void* const* d_in, const int* in_sizes, int n_in,
                              void* d_out, int out_size, void* d_ws, size_t ws_size,
                              hipStream_t stream) {
    const float* ts  = (const float*)d_in[0];
    const float* x0  = (const float*)d_in[1];
    const float* eps = (const float*)d_in[2];
    const float* fW0 = (const float*)d_in[3];
    const float* fb0 = (const float*)d_in[4];
    const float* fW1 = (const float*)d_in[5];
    const float* fb1 = (const float*)d_in[6];
    const float* fW2 = (const float*)d_in[7];
    const float* fb2 = (const float*)d_in[8];
    const float* gW0 = (const float*)d_in[9];
    const float* gb0 = (const float*)d_in[10];
    const float* gW1 = (const float*)d_in[11];
    const float* gb1 = (const float*)d_in[12];
    const float* gW2 = (const float*)d_in[13];
    const float* gb2 = (const float*)d_in[14];

    float* out  = (float*)d_out;
    float* Yout = out + 1;            // Y: (B,N,1) flat, row index r = b*N+n
    float* fv   = out + 1 + R_;       // final_value: (B,1)

    char* wsb = (char*)d_ws;
    float* xs           = (float*)wsb;                                          // B*N*2 f32 = 4MB
    unsigned int* wswz  = (unsigned int*)(wsb + (4 << 20));                     // fp8 frags, 128KB
    float* zdot         = (float*)(wsb + (4 << 20) + (256 << 10));              // 2MB
    float* partials     = (float*)(wsb + (4 << 20) + (256 << 10) + (2 << 20));  // 4KB

    hipLaunchKernelGGL(prep_weights, dim3(128), dim3(256), 0, stream, fW1, gW1, wswz);
    hipLaunchKernelGGL(traj_kernel, dim3(512), dim3(256), 0, stream, ts, x0, eps, xs, fv);
    hipLaunchKernelGGL(mlp_kernel, dim3(2 * GRID_MLP), dim3(512), 0, stream,
                       ts, eps, xs, wswz,
                       fW0, fb0, fb1, fW2, fb2,
                       gW0, gb0, gb1, gW2, gb2, Yout, zdot);
    hipLaunchKernelGGL(loss_partial_kernel, dim3(1024), dim3(256), 0, stream, Yout, fv, zdot, partials);
    hipLaunchKernelGGL(loss_final_kernel, dim3(1), dim3(256), 0, stream, partials, out);
}

// Round 12
// 174.762 us; speedup vs baseline: 1.3082x; 1.1085x over previous
//
#include <hip/hip_runtime.h>
#include <math.h>

#define B_ 2048
#define N_ 256
#define R_ (B_*N_)
#define MU_ 0.1f
#define SIGMA_ 0.2f
#define TILE_M 64
#define GRID_MLP 512
#define ITERS (R_ / TILE_M / GRID_MLP)   // 16

typedef __attribute__((ext_vector_type(4))) float f32x4;
typedef __attribute__((ext_vector_type(4))) int   i32x4;
typedef __attribute__((ext_vector_type(8))) int   i32x8;

// ---- convert fW1/gW1 (256x256 f32, k-major) to fp8-e4m3 K=128 MFMA fragments ----
// word idx = (((ki*16 + ct)*64 + lane)*8 + q) ; byte j of lane block holds
// W1[k = ki*128 + (lane>>4)*32 + j][c = ct*16 + (lane&15)]  (A/B symmetric map)
__global__ void prep_weights(const float* __restrict__ fW1, const float* __restrict__ gW1,
                             unsigned int* __restrict__ wswz) {
    int idx = blockIdx.x * 256 + threadIdx.x;   // u32-word index, 16384 words per MLP
    if (idx >= 2 * 16384) return;
    int m = idx >> 14, wi = idx & 16383;
    int frag = wi >> 9;                 // ki*16 + ct
    int lane = (wi >> 3) & 63, q = wi & 7;
    int ki = frag >> 4, ct = frag & 15;
    int k = ki * 128 + (lane >> 4) * 32 + q * 4;
    int c = ct * 16 + (lane & 15);
    const float* W = m ? gW1 : fW1;
    float v0 = W[(k + 0) * 256 + c];
    float v1 = W[(k + 1) * 256 + c];
    float v2 = W[(k + 2) * 256 + c];
    float v3 = W[(k + 3) * 256 + c];
    int u = __builtin_amdgcn_cvt_pk_fp8_f32(v0, v1, 0, false);
    u = __builtin_amdgcn_cvt_pk_fp8_f32(v2, v3, u, true);
    wswz[idx] = (unsigned int)u;
}

// ---- trajectory via wave-parallel prefix-product scan: one wave per batch row ----
__global__ void traj_kernel(const float* __restrict__ ts, const float* __restrict__ x0,
                            const float* __restrict__ eps, float* __restrict__ xs,
                            float* __restrict__ fv) {
    int gid = blockIdx.x * 256 + threadIdx.x;
    int b = gid >> 6, lane = gid & 63;
    int n0 = lane * 4;

    float t0 = ts[n0], t1 = ts[n0 + 1], t2 = ts[n0 + 2], t3 = ts[n0 + 3];
    float t4 = (n0 + 4 < N_) ? ts[n0 + 4] : t3;          // lane 63: h3 = 0
    float h0 = t1 - t0, h1 = t2 - t1, h2 = t3 - t2, h3 = t4 - t3;
    float s0 = sqrtf(h0), s1 = sqrtf(h1), s2 = sqrtf(h2), s3 = sqrtf(h3);

    const float4* e4 = (const float4*)(eps + (size_t)(b * N_ + n0) * 2);
    float4 ea = e4[0], eb = e4[1];
    float f0a = 1.f + MU_ * h0 + SIGMA_ * (ea.x * s0);
    float f0b = 1.f + MU_ * h0 + SIGMA_ * (ea.y * s0);
    float f1a = 1.f + MU_ * h1 + SIGMA_ * (ea.z * s1);
    float f1b = 1.f + MU_ * h1 + SIGMA_ * (ea.w * s1);
    float f2a = 1.f + MU_ * h2 + SIGMA_ * (eb.x * s2);
    float f2b = 1.f + MU_ * h2 + SIGMA_ * (eb.y * s2);
    float f3a = 1.f + MU_ * h3 + SIGMA_ * (eb.z * s3);
    float f3b = 1.f + MU_ * h3 + SIGMA_ * (eb.w * s3);

    float Pa = f0a * f1a * f2a * f3a;
    float Pb = f0b * f1b * f2b * f3b;
    float Sa = Pa, Sb = Pb;
#pragma unroll
    for (int d = 1; d < 64; d <<= 1) {
        float va = __shfl_up(Sa, d);
        float vb = __shfl_up(Sb, d);
        if (lane >= d) { Sa *= va; Sb *= vb; }
    }
    float Ea = __shfl_up(Sa, 1);
    float Eb = __shfl_up(Sb, 1);
    if (lane == 0) { Ea = 1.f; Eb = 1.f; }

    float x0a = x0[2 * b], x0b = x0[2 * b + 1];
    float xa0 = x0a * Ea, xb0 = x0b * Eb;
    float xa1 = xa0 * f0a, xb1 = xb0 * f0b;
    float xa2 = xa1 * f1a, xb2 = xb1 * f1b;
    float xa3 = xa2 * f2a, xb3 = xb2 * f2b;

    float4* xsv = (float4*)(xs + (size_t)(b * N_ + n0) * 2);
    xsv[0] = make_float4(xa0, xb0, xa1, xb1);
    xsv[1] = make_float4(xa2, xb2, xa3, xb3);
    if (lane == 63) fv[b] = xa3 * xa3 + xb3 * xb3;
}

// ---- fused MLP: MX-scaled fp8 K=128 MFMA, LDS-resident samples, reg-resident consts ----
// Merged f+g: grid 1024, MLP=blockIdx&1, bid=blockIdx>>1. TILE_M=64, ITERS=16.
// vs r11: (1) mfma_scale_f32_16x16x128_f8f6f4 (scale=127 => 1.0): 64->16 MFMA/wave/tile,
// 2x matrix rate; (2) 32B-block swizzle (k ^ (r&7)<<5) -> B-frags via ds_read_b128 x2;
// (3) b1/W2/bias hoisted from per-tile LDS reads into 24 resident VGPRs.
__global__ __launch_bounds__(512) void mlp_kernel(
        const float* __restrict__ ts, const float* __restrict__ eps, const float* __restrict__ xs,
        const unsigned int* __restrict__ wswz,
        const float* __restrict__ fW0, const float* __restrict__ fb0,
        const float* __restrict__ fb1, const float* __restrict__ fW2, const float* __restrict__ fb2,
        const float* __restrict__ gW0, const float* __restrict__ gb0,
        const float* __restrict__ gb1, const float* __restrict__ gW2, const float* __restrict__ gb2,
        float* __restrict__ Yout, float* __restrict__ zdot) {

    __shared__ __align__(16) unsigned char h0s[2][TILE_M * 256];   // fp8, 2 x 16KB, 32B-swizzled
    __shared__ float st[TILE_M * ITERS], sx1[TILE_M * ITERS], sx2[TILE_M * ITERS];
    __shared__ float sd0[TILE_M * ITERS], sd1[TILE_M * ITERS];
    __shared__ float red[2][8][TILE_M];

    const int MLP = blockIdx.x & 1;
    const int bid = blockIdx.x >> 1;

    const float* W0 = MLP ? gW0 : fW0;
    const float* b0 = MLP ? gb0 : fb0;
    const float* b1 = MLP ? gb1 : fb1;
    const float* W2 = MLP ? gW2 : fW2;
    const float* b2 = MLP ? gb2 : fb2;
    float* outp     = MLP ? zdot : Yout;

    const int tid  = threadIdx.x;
    const int lane = tid & 63;
    const int w    = tid >> 6;       // wave 0..7: cols [32w, 32w+32)
    const int arow = lane & 15;      // sample index within 16-row tile
    const int rg   = lane >> 4;      // k-block group / c-subgroup

    const int c0 = (tid & 63) * 4;   // layer0 col base
    const int row0 = (tid >> 6) * 8; // layer0 row base (8 rows/thread)
    f32x4 w0t = *(const f32x4*)(W0 + c0);
    f32x4 w0x = *(const f32x4*)(W0 + 256 + c0);
    f32x4 w0y = *(const f32x4*)(W0 + 512 + c0);
    f32x4 w0bv = *(const f32x4*)(b0 + c0);

    // layer1 bias + layer2 weights resident in VGPRs (were per-tile LDS reads)
    f32x4 bi0 = *(const f32x4*)(b1 + w * 32 + 4 * rg);
    f32x4 bi1 = *(const f32x4*)(b1 + w * 32 + 16 + 4 * rg);
    f32x4 w20v[2], w21v[2];
#pragma unroll
    for (int p = 0; p < 2; ++p) {
        int c = w * 32 + p * 16 + 4 * rg;
        if (MLP) {
            f32x4 lo = *(const f32x4*)(W2 + 2 * c);
            f32x4 hi = *(const f32x4*)(W2 + 2 * c + 4);
            w20v[p] = (f32x4){lo[0], lo[2], hi[0], hi[2]};
            w21v[p] = (f32x4){lo[1], lo[3], hi[1], hi[3]};
        } else {
            w20v[p] = *(const f32x4*)(W2 + c);
            w21v[p] = (f32x4){0.f, 0.f, 0.f, 0.f};
        }
    }
    const float b20 = b2[0];
    const float b21 = MLP ? b2[1] : 0.f;

    // resident A-fragments of W1^T (fp8, K=128): 2 ki x 2 ct x 8 VGPR = 32 VGPRs
    i32x8 afrag[2][2];
    {
        const i32x4* wsw4 = (const i32x4*)(wswz + MLP * 16384);
#pragma unroll
        for (int ki = 0; ki < 2; ++ki)
#pragma unroll
            for (int p = 0; p < 2; ++p) {
                int base = ((ki * 16 + (w * 2 + p)) * 64 + lane) * 2;
                i32x4 lo = wsw4[base], hi = wsw4[base + 1];
                afrag[ki][p] = __builtin_shufflevector(lo, hi, 0, 1, 2, 3, 4, 5, 6, 7);
            }
    }

    // ---- preload ALL per-block sample data to LDS (coalesced, once) ----
#pragma unroll
    for (int q = 0; q < 2; ++q) {
        int s = q * 512 + tid;                 // 0..1023
        int it = s >> 6, i = s & 63;
        int r = (bid + it * GRID_MLP) * TILE_M + i;
        int n = r & (N_ - 1);
        float2 xv = ((const float2*)xs)[r];
        float tv = ts[n];
        st[s] = tv; sx1[s] = xv.x; sx2[s] = xv.y;
        if (MLP) {
            float sdt = (n < N_ - 1) ? sqrtf(ts[n + 1] - tv) : 0.f;
            float2 ev = ((const float2*)eps)[r];
            sd0[s] = ev.x * sdt; sd1[s] = ev.y * sdt;
        }
    }
    __syncthreads();

    // layer0 tile 0 -> h0s[0]
#pragma unroll
    for (int ii = 0; ii < 8; ++ii) {
        int r = row0 + ii;
        float t = st[r], x1 = sx1[r], x2 = sx2[r];
        f32x4 h;
#pragma unroll
        for (int j = 0; j < 4; ++j)
            h[j] = fmaxf(fmaf(t, w0t[j], fmaf(x1, w0x[j], fmaf(x2, w0y[j], w0bv[j]))), 0.f);
        int q = __builtin_amdgcn_cvt_pk_fp8_f32(h[0], h[1], 0, false);
        q = __builtin_amdgcn_cvt_pk_fp8_f32(h[2], h[3], q, true);
        int off = r * 256 + (c0 ^ ((r & 7) << 5));
        *(unsigned int*)(h0s[0] + off) = (unsigned int)q;
    }
    __syncthreads();

    for (int t = 0; t < ITERS; ++t) {
        const int sb = t & 1;

        // out-write for tile t-1 (only in-loop global op)
        if (t > 0 && tid < TILE_M) {
            const int pb = sb ^ 1;
            float s = red[pb][0][tid] + red[pb][1][tid] + red[pb][2][tid] + red[pb][3][tid]
                    + red[pb][4][tid] + red[pb][5][tid] + red[pb][6][tid] + red[pb][7][tid];
            if (!MLP) s += b20;
            outp[(bid + (t - 1) * GRID_MLP) * TILE_M + tid] = s;
        }

        // MFMA(t) <- h0s[sb]: 2 ki x 4 rt x 2 p = 16 MX-scaled MFMA (K=128, scale=1.0)
        f32x4 acc[4][2];
#pragma unroll
        for (int rt = 0; rt < 4; ++rt) { acc[rt][0] = bi0; acc[rt][1] = bi1; }
#pragma unroll
        for (int ki = 0; ki < 2; ++ki) {
#pragma unroll
            for (int rt = 0; rt < 4; ++rt) {
                int row = rt * 16 + arow;
                int roff = row * 256 + ((ki * 128 + rg * 32) ^ ((row & 7) << 5));
                i32x4 blo = *(const i32x4*)(h0s[sb] + roff);
                i32x4 bhi = *(const i32x4*)(h0s[sb] + roff + 16);
                i32x8 bf = __builtin_shufflevector(blo, bhi, 0, 1, 2, 3, 4, 5, 6, 7);
                acc[rt][0] = __builtin_amdgcn_mfma_scale_f32_16x16x128_f8f6f4(
                                 afrag[ki][0], bf, acc[rt][0], 0, 0, 0, 127, 0, 127);
                acc[rt][1] = __builtin_amdgcn_mfma_scale_f32_16x16x128_f8f6f4(
                                 afrag[ki][1], bf, acc[rt][1], 0, 0, 0, 127, 0, 127);
            }
        }

        // epilogue -> red[sb] (consts from registers)
#pragma unroll
        for (int rt = 0; rt < 4; ++rt) {
            float A0 = 0.f, A1 = 0.f;
#pragma unroll
            for (int p = 0; p < 2; ++p) {
#pragma unroll
                for (int i = 0; i < 4; ++i) {
                    float v = fmaxf(acc[rt][p][i], 0.f);
                    A0 = fmaf(v, w20v[p][i], A0);
                    if (MLP) A1 = fmaf(v, w21v[p][i], A1);
                }
            }
            A0 += __shfl_xor(A0, 16); A0 += __shfl_xor(A0, 32);
            if (MLP) { A1 += __shfl_xor(A1, 16); A1 += __shfl_xor(A1, 32); }
            if (rg == 0) {
                int row = rt * 16 + arow;
                float rv;
                if (MLP) {
                    int s = t * TILE_M + row;
                    float d0 = sd0[s], d1 = sd1[s];
                    rv = fmaf(A1, d1, A0 * d0);
                    if (w == 0) rv += fmaf(b21, d1, b20 * d0);
                } else {
                    rv = A0;
                }
                red[sb][w][row] = rv;
            }
        }

        // layer0(t+1) -> h0s[sb^1] (LDS-resident samples only)
        if (t + 1 < ITERS) {
            const int sbase = (t + 1) * TILE_M;
#pragma unroll
            for (int ii = 0; ii < 8; ++ii) {
                int r = row0 + ii;
                int s = sbase + r;
                float tv = st[s], x1 = sx1[s], x2 = sx2[s];
                f32x4 h;
#pragma unroll
                for (int j = 0; j < 4; ++j)
                    h[j] = fmaxf(fmaf(tv, w0t[j], fmaf(x1, w0x[j], fmaf(x2, w0y[j], w0bv[j]))), 0.f);
                int q = __builtin_amdgcn_cvt_pk_fp8_f32(h[0], h[1], 0, false);
                q = __builtin_amdgcn_cvt_pk_fp8_f32(h[2], h[3], q, true);
                int off = r * 256 + (c0 ^ ((r & 7) << 5));
                *(unsigned int*)(h0s[sb ^ 1] + off) = (unsigned int)q;
            }
        }
        __syncthreads();   // single per-tile barrier (LDS-only drain)
    }
    // final out-write (tile ITERS-1)
    if (tid < TILE_M) {
        const int pb = (ITERS - 1) & 1;
        float s = red[pb][0][tid] + red[pb][1][tid] + red[pb][2][tid] + red[pb][3][tid]
                + red[pb][4][tid] + red[pb][5][tid] + red[pb][6][tid] + red[pb][7][tid];
        if (!MLP) s += b20;
        outp[(bid + (ITERS - 1) * GRID_MLP) * TILE_M + tid] = s;
    }
}

// ---- loss: sum over r of (Y + Zdot - target)^2, /B ----
__global__ void loss_partial_kernel(const float* __restrict__ Yout, const float* __restrict__ fv,
                                    const float* __restrict__ zdot, float* __restrict__ partials) {
    __shared__ float wred[4];
    int tid = threadIdx.x;
    float s = 0.f;
    for (int r = blockIdx.x * 256 + tid; r < R_; r += gridDim.x * 256) {
        int n = r & (N_ - 1);
        float pred = Yout[r] + zdot[r];
        float target = (n == N_ - 1) ? fv[r >> 8] : Yout[r + 1];
        float d = pred - target;
        s = fmaf(d, d, s);
    }
#pragma unroll
    for (int m = 1; m < 64; m <<= 1) s += __shfl_xor(s, m);
    if ((tid & 63) == 0) wred[tid >> 6] = s;
    __syncthreads();
    if (tid == 0) partials[blockIdx.x] = wred[0] + wred[1] + wred[2] + wred[3];
}

__global__ void loss_final_kernel(const float* __restrict__ partials, float* __restrict__ out) {
    __shared__ float wred[4];
    int tid = threadIdx.x;
    float s = partials[tid] + partials[256 + tid] + partials[512 + tid] + partials[768 + tid];
#pragma unroll
    for (int m = 1; m < 64; m <<= 1) s += __shfl_xor(s, m);
    if ((tid & 63) == 0) wred[tid >> 6] = s;
    __syncthreads();
    if (tid == 0) out[0] = (wred[0] + wred[1] + wred[2] + wred[3]) * (1.0f / B_);
}

extern "C" void kernel_launch(void* const* d_in, const int* in_sizes, int n_in,
                              void* d_out, int out_size, void* d_ws, size_t ws_size,
                              hipStream_t stream) {
    const float* ts  = (const float*)d_in[0];
    const float* x0  = (const float*)d_in[1];
    const float* eps = (const float*)d_in[2];
    const float* fW0 = (const float*)d_in[3];
    const float* fb0 = (const float*)d_in[4];
    const float* fW1 = (const float*)d_in[5];
    const float* fb1 = (const float*)d_in[6];
    const float* fW2 = (const float*)d_in[7];
    const float* fb2 = (const float*)d_in[8];
    const float* gW0 = (const float*)d_in[9];
    const float* gb0 = (const float*)d_in[10];
    const float* gW1 = (const float*)d_in[11];
    const float* gb1 = (const float*)d_in[12];
    const float* gW2 = (const float*)d_in[13];
    const float* gb2 = (const float*)d_in[14];

    float* out  = (float*)d_out;
    float* Yout = out + 1;            // Y: (B,N,1) flat, row index r = b*N+n
    float* fv   = out + 1 + R_;       // final_value: (B,1)

    char* wsb = (char*)d_ws;
    float* xs           = (float*)wsb;                                          // B*N*2 f32 = 4MB
    unsigned int* wswz  = (unsigned int*)(wsb + (4 << 20));                     // fp8 K=128 frags, 128KB
    float* zdot         = (float*)(wsb + (4 << 20) + (256 << 10));              // 2MB
    float* partials     = (float*)(wsb + (4 << 20) + (256 << 10) + (2 << 20));  // 4KB

    hipLaunchKernelGGL(prep_weights, dim3(128), dim3(256), 0, stream, fW1, gW1, wswz);
    hipLaunchKernelGGL(traj_kernel, dim3(512), dim3(256), 0, stream, ts, x0, eps, xs, fv);
    hipLaunchKernelGGL(mlp_kernel, dim3(2 * GRID_MLP), dim3(512), 0, stream,
                       ts, eps, xs, wswz,
                       fW0, fb0, fb1, fW2, fb2,
                       gW0, gb0, gb1, gW2, gb2, Yout, zdot);
    hipLaunchKernelGGL(loss_partial_kernel, dim3(1024), dim3(256), 0, stream, Yout, fv, zdot, partials);
    hipLaunchKernelGGL(loss_final_kernel, dim3(1), dim3(256), 0, stream, partials, out);
}

// Round 13
// 154.128 us; speedup vs baseline: 1.4833x; 1.1339x over previous
//
#include <hip/hip_runtime.h>
#include <math.h>

#define B_ 2048
#define N_ 256
#define R_ (B_*N_)
#define MU_ 0.1f
#define SIGMA_ 0.2f
#define TILE_M 64
#define GRID_MLP 512
#define ITERS (R_ / TILE_M / GRID_MLP)   // 16

typedef __attribute__((ext_vector_type(4))) float f32x4;
typedef __attribute__((ext_vector_type(2))) int   i32x2;
typedef __attribute__((ext_vector_type(8))) int   i32x8;

// ---- convert fW1/gW1 (256x256 f32, k-major) to fp8-e4m3 K=128 MFMA fragments ----
// word idx = (((ki*16 + ct)*64 + lane)*8 + q) ; byte j of lane block holds
// W1[k = ki*128 + (lane>>4)*32 + j][c = ct*16 + (lane&15)]  (A/B symmetric map)
__global__ void prep_weights(const float* __restrict__ fW1, const float* __restrict__ gW1,
                             unsigned int* __restrict__ wswz) {
    int idx = blockIdx.x * 256 + threadIdx.x;   // u32-word index, 16384 words per MLP
    if (idx >= 2 * 16384) return;
    int m = idx >> 14, wi = idx & 16383;
    int frag = wi >> 9;                 // ki*16 + ct
    int lane = (wi >> 3) & 63, q = wi & 7;
    int ki = frag >> 4, ct = frag & 15;
    int k = ki * 128 + (lane >> 4) * 32 + q * 4;
    int c = ct * 16 + (lane & 15);
    const float* W = m ? gW1 : fW1;
    float v0 = W[(k + 0) * 256 + c];
    float v1 = W[(k + 1) * 256 + c];
    float v2 = W[(k + 2) * 256 + c];
    float v3 = W[(k + 3) * 256 + c];
    int u = __builtin_amdgcn_cvt_pk_fp8_f32(v0, v1, 0, false);
    u = __builtin_amdgcn_cvt_pk_fp8_f32(v2, v3, u, true);
    wswz[idx] = (unsigned int)u;
}

// ---- trajectory via wave-parallel prefix-product scan: one wave per batch row ----
__global__ void traj_kernel(const float* __restrict__ ts, const float* __restrict__ x0,
                            const float* __restrict__ eps, float* __restrict__ xs,
                            float* __restrict__ fv) {
    int gid = blockIdx.x * 256 + threadIdx.x;
    int b = gid >> 6, lane = gid & 63;
    int n0 = lane * 4;

    float t0 = ts[n0], t1 = ts[n0 + 1], t2 = ts[n0 + 2], t3 = ts[n0 + 3];
    float t4 = (n0 + 4 < N_) ? ts[n0 + 4] : t3;          // lane 63: h3 = 0
    float h0 = t1 - t0, h1 = t2 - t1, h2 = t3 - t2, h3 = t4 - t3;
    float s0 = sqrtf(h0), s1 = sqrtf(h1), s2 = sqrtf(h2), s3 = sqrtf(h3);

    const float4* e4 = (const float4*)(eps + (size_t)(b * N_ + n0) * 2);
    float4 ea = e4[0], eb = e4[1];
    float f0a = 1.f + MU_ * h0 + SIGMA_ * (ea.x * s0);
    float f0b = 1.f + MU_ * h0 + SIGMA_ * (ea.y * s0);
    float f1a = 1.f + MU_ * h1 + SIGMA_ * (ea.z * s1);
    float f1b = 1.f + MU_ * h1 + SIGMA_ * (ea.w * s1);
    float f2a = 1.f + MU_ * h2 + SIGMA_ * (eb.x * s2);
    float f2b = 1.f + MU_ * h2 + SIGMA_ * (eb.y * s2);
    float f3a = 1.f + MU_ * h3 + SIGMA_ * (eb.z * s3);
    float f3b = 1.f + MU_ * h3 + SIGMA_ * (eb.w * s3);

    float Pa = f0a * f1a * f2a * f3a;
    float Pb = f0b * f1b * f2b * f3b;
    float Sa = Pa, Sb = Pb;
#pragma unroll
    for (int d = 1; d < 64; d <<= 1) {
        float va = __shfl_up(Sa, d);
        float vb = __shfl_up(Sb, d);
        if (lane >= d) { Sa *= va; Sb *= vb; }
    }
    float Ea = __shfl_up(Sa, 1);
    float Eb = __shfl_up(Sb, 1);
    if (lane == 0) { Ea = 1.f; Eb = 1.f; }

    float x0a = x0[2 * b], x0b = x0[2 * b + 1];
    float xa0 = x0a * Ea, xb0 = x0b * Eb;
    float xa1 = xa0 * f0a, xb1 = xb0 * f0b;
    float xa2 = xa1 * f1a, xb2 = xb1 * f1b;
    float xa3 = xa2 * f2a, xb3 = xb2 * f2b;

    float4* xsv = (float4*)(xs + (size_t)(b * N_ + n0) * 2);
    xsv[0] = make_float4(xa0, xb0, xa1, xb1);
    xsv[1] = make_float4(xa2, xb2, xa3, xb3);
    if (lane == 63) fv[b] = xa3 * xa3 + xb3 * xb3;
}

// ---- fused MLP: MX-scaled fp8 K=128 MFMA, LDS-resident samples ----
// Merged f+g: grid 1024, MLP=blockIdx&1, bid=blockIdx>>1. TILE_M=64, ITERS=16.
// vs r12: (1) B-frag reads = 4x ds_read_b64 with r10's 0-conflict 8B swizzle
// ((row&15)<<3) instead of b128+32B swizzle (which was 4-way conflicted);
// (2) samples packed float4/float2 (8 b128 reads in layer0 vs 24 b32);
// (3) shuffle-free epilogue: per-lane partial -> red2[row][w*4+rg] (stride 36,
// all-32-bank write), out-write sums 32 floats via 8 b128; (4) setprio on MFMA.
__global__ __launch_bounds__(512) void mlp_kernel(
        const float* __restrict__ ts, const float* __restrict__ eps, const float* __restrict__ xs,
        const unsigned int* __restrict__ wswz,
        const float* __restrict__ fW0, const float* __restrict__ fb0,
        const float* __restrict__ fb1, const float* __restrict__ fW2, const float* __restrict__ fb2,
        const float* __restrict__ gW0, const float* __restrict__ gb0,
        const float* __restrict__ gb1, const float* __restrict__ gW2, const float* __restrict__ gb2,
        float* __restrict__ Yout, float* __restrict__ zdot) {

    __shared__ __align__(16) unsigned char h0s[2][TILE_M * 256];   // fp8, 2 x 16KB, 8B swizzle
    __shared__ __align__(16) float4 sfx[TILE_M * ITERS];           // {t, x1, x2, -} 16KB
    __shared__ __align__(16) float2 sd[TILE_M * ITERS];            // {d0, d1} 8KB
    __shared__ __align__(16) float red2[2][TILE_M][36];            // partials, 18KB

    const int MLP = blockIdx.x & 1;
    const int bid = blockIdx.x >> 1;

    const float* W0 = MLP ? gW0 : fW0;
    const float* b0 = MLP ? gb0 : fb0;
    const float* b1 = MLP ? gb1 : fb1;
    const float* W2 = MLP ? gW2 : fW2;
    const float* b2 = MLP ? gb2 : fb2;
    float* outp     = MLP ? zdot : Yout;

    const int tid  = threadIdx.x;
    const int lane = tid & 63;
    const int w    = tid >> 6;       // wave 0..7: cols [32w, 32w+32)
    const int arow = lane & 15;      // sample index within 16-row tile
    const int rg   = lane >> 4;      // k-block group / c-subgroup

    const int c0 = (tid & 63) * 4;   // layer0 col base
    const int row0 = (tid >> 6) * 8; // layer0 row base (8 rows/thread)
    f32x4 w0t = *(const f32x4*)(W0 + c0);
    f32x4 w0x = *(const f32x4*)(W0 + 256 + c0);
    f32x4 w0y = *(const f32x4*)(W0 + 512 + c0);
    f32x4 w0bv = *(const f32x4*)(b0 + c0);

    // layer1 bias + layer2 weights resident in VGPRs
    f32x4 bi0 = *(const f32x4*)(b1 + w * 32 + 4 * rg);
    f32x4 bi1 = *(const f32x4*)(b1 + w * 32 + 16 + 4 * rg);
    f32x4 w20v[2], w21v[2];
#pragma unroll
    for (int p = 0; p < 2; ++p) {
        int c = w * 32 + p * 16 + 4 * rg;
        if (MLP) {
            f32x4 lo = *(const f32x4*)(W2 + 2 * c);
            f32x4 hi = *(const f32x4*)(W2 + 2 * c + 4);
            w20v[p] = (f32x4){lo[0], lo[2], hi[0], hi[2]};
            w21v[p] = (f32x4){lo[1], lo[3], hi[1], hi[3]};
        } else {
            w20v[p] = *(const f32x4*)(W2 + c);
            w21v[p] = (f32x4){0.f, 0.f, 0.f, 0.f};
        }
    }
    const float b20 = b2[0];
    const float b21 = MLP ? b2[1] : 0.f;

    // resident A-fragments of W1^T (fp8, K=128): 2 ki x 2 ct x 8 VGPR = 32 VGPRs
    i32x8 afrag[2][2];
    {
        const i32x2* wsw2 = (const i32x2*)(wswz + MLP * 16384);
#pragma unroll
        for (int ki = 0; ki < 2; ++ki)
#pragma unroll
            for (int p = 0; p < 2; ++p) {
                int base = ((ki * 16 + (w * 2 + p)) * 64 + lane) * 4;
                i32x2 a0 = wsw2[base], a1 = wsw2[base + 1], a2 = wsw2[base + 2], a3 = wsw2[base + 3];
                afrag[ki][p] = (i32x8){a0[0], a0[1], a1[0], a1[1], a2[0], a2[1], a3[0], a3[1]};
            }
    }

    // ---- preload ALL per-block sample data to LDS (coalesced, once) ----
#pragma unroll
    for (int q = 0; q < 2; ++q) {
        int s = q * 512 + tid;                 // 0..1023
        int it = s >> 6, i = s & 63;
        int r = (bid + it * GRID_MLP) * TILE_M + i;
        int n = r & (N_ - 1);
        float2 xv = ((const float2*)xs)[r];
        float tv = ts[n];
        sfx[s] = make_float4(tv, xv.x, xv.y, 0.f);
        if (MLP) {
            float sdt = (n < N_ - 1) ? sqrtf(ts[n + 1] - tv) : 0.f;
            float2 ev = ((const float2*)eps)[r];
            sd[s] = make_float2(ev.x * sdt, ev.y * sdt);
        }
    }
    __syncthreads();

    // layer0 tile 0 -> h0s[0]
#pragma unroll
    for (int ii = 0; ii < 8; ++ii) {
        int r = row0 + ii;
        float4 v = sfx[r];
        f32x4 h;
#pragma unroll
        for (int j = 0; j < 4; ++j)
            h[j] = fmaxf(fmaf(v.x, w0t[j], fmaf(v.y, w0x[j], fmaf(v.z, w0y[j], w0bv[j]))), 0.f);
        int q = __builtin_amdgcn_cvt_pk_fp8_f32(h[0], h[1], 0, false);
        q = __builtin_amdgcn_cvt_pk_fp8_f32(h[2], h[3], q, true);
        int off = r * 256 + (c0 ^ ((r & 15) << 3));
        *(unsigned int*)(h0s[0] + off) = (unsigned int)q;
    }
    __syncthreads();

    for (int t = 0; t < ITERS; ++t) {
        const int sb = t & 1;

        // out-write for tile t-1 (only in-loop global op)
        if (t > 0 && tid < TILE_M) {
            const int pb = sb ^ 1;
            const float* rr = red2[pb][tid];
            float s = 0.f;
#pragma unroll
            for (int j = 0; j < 32; j += 4) {
                f32x4 v = *(const f32x4*)(rr + j);
                s += (v[0] + v[1]) + (v[2] + v[3]);
            }
            if (!MLP) s += b20;
            outp[(bid + (t - 1) * GRID_MLP) * TILE_M + tid] = s;
        }

        // MFMA(t) <- h0s[sb]: 2 ki x 4 rt x 2 p = 16 MX-scaled MFMA (K=128, scale=1.0)
        f32x4 acc[4][2];
#pragma unroll
        for (int rt = 0; rt < 4; ++rt) { acc[rt][0] = bi0; acc[rt][1] = bi1; }
        __builtin_amdgcn_s_setprio(1);
#pragma unroll
        for (int ki = 0; ki < 2; ++ki) {
#pragma unroll
            for (int rt = 0; rt < 4; ++rt) {
                int row = rt * 16 + arow;
                const int rsw = (row & 15) << 3;
                const unsigned char* bp = h0s[sb] + row * 256;
                const int kb = ki * 128 + rg * 32;
                i32x2 q0 = *(const i32x2*)(bp + ((kb +  0) ^ rsw));
                i32x2 q1 = *(const i32x2*)(bp + ((kb +  8) ^ rsw));
                i32x2 q2 = *(const i32x2*)(bp + ((kb + 16) ^ rsw));
                i32x2 q3 = *(const i32x2*)(bp + ((kb + 24) ^ rsw));
                i32x8 bf = (i32x8){q0[0], q0[1], q1[0], q1[1], q2[0], q2[1], q3[0], q3[1]};
                acc[rt][0] = __builtin_amdgcn_mfma_scale_f32_16x16x128_f8f6f4(
                                 afrag[ki][0], bf, acc[rt][0], 0, 0, 0, 127, 0, 127);
                acc[rt][1] = __builtin_amdgcn_mfma_scale_f32_16x16x128_f8f6f4(
                                 afrag[ki][1], bf, acc[rt][1], 0, 0, 0, 127, 0, 127);
            }
        }
        __builtin_amdgcn_s_setprio(0);

        // epilogue -> red2[sb] (per-lane partial; no cross-lane shuffles)
#pragma unroll
        for (int rt = 0; rt < 4; ++rt) {
            float A0 = 0.f, A1 = 0.f;
#pragma unroll
            for (int p = 0; p < 2; ++p) {
#pragma unroll
                for (int i = 0; i < 4; ++i) {
                    float v = fmaxf(acc[rt][p][i], 0.f);
                    A0 = fmaf(v, w20v[p][i], A0);
                    if (MLP) A1 = fmaf(v, w21v[p][i], A1);
                }
            }
            int row = rt * 16 + arow;
            float rv;
            if (MLP) {
                float2 dv = sd[t * TILE_M + row];
                rv = fmaf(A1, dv.y, A0 * dv.x);
                if (w == 0) rv += fmaf(b21, dv.y, b20 * dv.x);
            } else {
                rv = A0;
            }
            red2[sb][row][w * 4 + rg] = rv;
        }

        // layer0(t+1) -> h0s[sb^1] (LDS-resident samples only)
        if (t + 1 < ITERS) {
            const int sbase = (t + 1) * TILE_M;
#pragma unroll
            for (int ii = 0; ii < 8; ++ii) {
                int r = row0 + ii;
                float4 v = sfx[sbase + r];
                f32x4 h;
#pragma unroll
                for (int j = 0; j < 4; ++j)
                    h[j] = fmaxf(fmaf(v.x, w0t[j], fmaf(v.y, w0x[j], fmaf(v.z, w0y[j], w0bv[j]))), 0.f);
                int q = __builtin_amdgcn_cvt_pk_fp8_f32(h[0], h[1], 0, false);
                q = __builtin_amdgcn_cvt_pk_fp8_f32(h[2], h[3], q, true);
                int off = r * 256 + (c0 ^ ((r & 15) << 3));
                *(unsigned int*)(h0s[sb ^ 1] + off) = (unsigned int)q;
            }
        }
        __syncthreads();   // single per-tile barrier (LDS-only drain)
    }
    // final out-write (tile ITERS-1)
    if (tid < TILE_M) {
        const int pb = (ITERS - 1) & 1;
        const float* rr = red2[pb][tid];
        float s = 0.f;
#pragma unroll
        for (int j = 0; j < 32; j += 4) {
            f32x4 v = *(const f32x4*)(rr + j);
            s += (v[0] + v[1]) + (v[2] + v[3]);
        }
        if (!MLP) s += b20;
        outp[(bid + (ITERS - 1) * GRID_MLP) * TILE_M + tid] = s;
    }
}

// ---- loss: sum over r of (Y + Zdot - target)^2, /B ----
__global__ void loss_partial_kernel(const float* __restrict__ Yout, const float* __restrict__ fv,
                                    const float* __restrict__ zdot, float* __restrict__ partials) {
    __shared__ float wred[4];
    int tid = threadIdx.x;
    float s = 0.f;
    for (int r = blockIdx.x * 256 + tid; r < R_; r += gridDim.x * 256) {
        int n = r & (N_ - 1);
        float pred = Yout[r] + zdot[r];
        float target = (n == N_ - 1) ? fv[r >> 8] : Yout[r + 1];
        float d = pred - target;
        s = fmaf(d, d, s);
    }
#pragma unroll
    for (int m = 1; m < 64; m <<= 1) s += __shfl_xor(s, m);
    if ((tid & 63) == 0) wred[tid >> 6] = s;
    __syncthreads();
    if (tid == 0) partials[blockIdx.x] = wred[0] + wred[1] + wred[2] + wred[3];
}

__global__ void loss_final_kernel(const float* __restrict__ partials, float* __restrict__ out) {
    __shared__ float wred[4];
    int tid = threadIdx.x;
    float s = partials[tid] + partials[256 + tid] + partials[512 + tid] + partials[768 + tid];
#pragma unroll
    for (int m = 1; m < 64; m <<= 1) s += __shfl_xor(s, m);
    if ((tid & 63) == 0) wred[tid >> 6] = s;
    __syncthreads();
    if (tid == 0) out[0] = (wred[0] + wred[1] + wred[2] + wred[3]) * (1.0f / B_);
}

extern "C" void kernel_launch(void* const* d_in, const int* in_sizes, int n_in,
                              void* d_out, int out_size, void* d_ws, size_t ws_size,
                              hipStream_t stream) {
    const float* ts  = (const float*)d_in[0];
    const float* x0  = (const float*)d_in[1];
    const float* eps = (const float*)d_in[2];
    const float* fW0 = (const float*)d_in[3];
    const float* fb0 = (const float*)d_in[4];
    const float* fW1 = (const float*)d_in[5];
    const float* fb1 = (const float*)d_in[6];
    const float* fW2 = (const float*)d_in[7];
    const float* fb2 = (const float*)d_in[8];
    const float* gW0 = (const float*)d_in[9];
    const float* gb0 = (const float*)d_in[10];
    const float* gW1 = (const float*)d_in[11];
    const float* gb1 = (const float*)d_in[12];
    const float* gW2 = (const float*)d_in[13];
    const float* gb2 = (const float*)d_in[14];

    float* out  = (float*)d_out;
    float* Yout = out + 1;            // Y: (B,N,1) flat, row index r = b*N+n
    float* fv   = out + 1 + R_;       // final_value: (B,1)

    char* wsb = (char*)d_ws;
    float* xs           = (float*)wsb;                                          // B*N*2 f32 = 4MB
    unsigned int* wswz  = (unsigned int*)(wsb + (4 << 20));                     // fp8 K=128 frags, 128KB
    float* zdot         = (float*)(wsb + (4 << 20) + (256 << 10));              // 2MB
    float* partials     = (float*)(wsb + (4 << 20) + (256 << 10) + (2 << 20));  // 4KB

    hipLaunchKernelGGL(prep_weights, dim3(128), dim3(256), 0, stream, fW1, gW1, wswz);
    hipLaunchKernelGGL(traj_kernel, dim3(512), dim3(256), 0, stream, ts, x0, eps, xs, fv);
    hipLaunchKernelGGL(mlp_kernel, dim3(2 * GRID_MLP), dim3(512), 0, stream,
                       ts, eps, xs, wswz,
                       fW0, fb0, fb1, fW2, fb2,
                       gW0, gb0, gb1, gW2, gb2, Yout, zdot);
    hipLaunchKernelGGL(loss_partial_kernel, dim3(1024), dim3(256), 0, stream, Yout, fv, zdot, partials);
    hipLaunchKernelGGL(loss_final_kernel, dim3(1), dim3(256), 0, stream, partials, out);
}